// Round 1
// baseline (243.103 us; speedup 1.0000x reference)
//
#include <hip/hip_runtime.h>

// Soft decision tree DEPTH=8, 255 internal nodes (heap order), 256 leaves,
// 10 classes, B=131072, 32 feats. fp32 in/out.
//
// R5 = R4 with the depth-7 leaf accumulation switched from plain LDS RMW
// (ds_read + v_add + ds_write, alias-serialized: each RMW must wait for the
// previous write since two leaves can share a class slot) to fire-and-forget
// LDS atomics (atomicAdd on __shared__ with unused result -> ds_add_f32,
// no-return). This removes the serialized read-latency chain that R4's
// accA/accB split only partially mitigated, halves the DS ops on the leaf
// path, and lets the A/B arrays merge into ONE accumulator array:
//   - slots remain THREAD-private ((cls<<8)+t), so no contention; hardware
//     handles the rare same-thread r.z==r.w collision,
//   - LDS/block = 1016 + 2048 + 16384 + 10240 = 29688 B -> 5 blocks/CU
//     (launch_bounds(256,5) caps VGPR at 102 so the 5th block is resident),
//   - epilogue merges both tree halves: 2 reads per output (was 4).
// Unchanged from R4: 2 threads/row (4096 waves), packed node records
// (b64 depths 0..6 / b128 depth 7 incl. leaf classes), transposed
// conflict-free s_xT pre-scaled by log2e, depth-3 probs in regs.

#define NFEAT 32
#define NCLS  10
#define TPB   256
#define RPB   128          // rows per block (2 threads per row)
#define L2E   1.4426950408889634f

__device__ __forceinline__ float fexp2(float z) {
#if __has_builtin(__builtin_amdgcn_exp2f)
  return __builtin_amdgcn_exp2f(z);   // raw v_exp_f32
#else
  return exp2f(z);
#endif
}
__device__ __forceinline__ float frcp(float z) {
#if __has_builtin(__builtin_amdgcn_rcpf)
  return __builtin_amdgcn_rcpf(z);    // raw v_rcp_f32
#else
  return 1.0f / z;
#endif
}

// sigmoid(x-t): e = exp2(t2 - x2); act = 1/(1+e); 1-act = e*act
__device__ __forceinline__ void evaln(const int2* nd, const float* xT,
                                      int n, int row, float p,
                                      float& pl, float& pr) {
  const int2 r = nd[n];                        // ds_read_b64, broadcast (wave-uniform addr)
  const float x2 = xT[(r.y << 7) + row];       // ds_read_b32, lane-linear
  const float e = fexp2(__int_as_float(r.x) - x2);
  const float a = frcp(1.0f + e);
  pr = p * a;
  pl = pr * e;
}

template <int D>
__device__ __forceinline__ void dfs(const int2* nd, const int4* nd7,
                                    const float* xT, float* acc,
                                    int n, int t, int row, float p) {
  if constexpr (D == 7) {
    const int4 r = nd7[n - 127];               // ds_read_b128, broadcast
    const float x2 = xT[(r.y << 7) + row];
    const float e = fexp2(__int_as_float(r.x) - x2);
    const float a = frcp(1.0f + e);
    const float pr = p * a;
    const float pl = pr * e;
    atomicAdd(&acc[(r.z << 8) + t], pl);       // ds_add_f32, no return: no RMW chain
    atomicAdd(&acc[(r.w << 8) + t], pr);
  } else {
    float pl, pr;
    evaln(nd, xT, n, row, p, pl, pr);
    dfs<D + 1>(nd, nd7, xT, acc, 2 * n + 1, t, row, pl);
    dfs<D + 1>(nd, nd7, xT, acc, 2 * n + 2, t, row, pr);
  }
}

__global__ __launch_bounds__(TPB, 5)
void dt_kernel(const float* __restrict__ x,
               const float* __restrict__ thr,
               const int*   __restrict__ feats,
               const int*   __restrict__ leafc,
               float*       __restrict__ out) {
  __shared__ int2  s_nd[127];          // depths 0..6: {t*log2e bits, feat}
  __shared__ int4  s_nd7[128];         // depth 7: {t*log2e bits, feat, lcL, lcR}
  __shared__ float s_xT[NFEAT * RPB];  // transposed, pre-scaled by log2e
  __shared__ float s_acc[NCLS * TPB];  // per-THREAD class accumulators (atomic)

  const int t   = threadIdx.x;
  const int row = t & (RPB - 1);
  const int h   = t >> 7;              // wave-uniform half select

  // --- stage node params (once) ---
  if (t < 127) {
    s_nd[t] = make_int2(__float_as_int(thr[t] * L2E), feats[t]);
  } else if (t < 255) {
    const int n7 = t - 127;
    s_nd7[n7] = make_int4(__float_as_int(thr[t] * L2E), feats[t],
                          leafc[2 * n7], leafc[2 * n7 + 1]);
  }

  // --- stage x: coalesced float4 reads, transposed LDS writes ---
  const float4* xg = (const float4*)x + (size_t)blockIdx.x * (RPB * NFEAT / 4);
#pragma unroll
  for (int k = 0; k < 4; ++k) {
    const int i4 = k * TPB + t;                // 0..1023
    const float4 v = xg[i4];
    const int r  = i4 >> 3;                    // local row
    const int c0 = (i4 & 7) * 4;               // first of 4 feature columns
    s_xT[(c0 + 0) * RPB + r] = v.x * L2E;
    s_xT[(c0 + 1) * RPB + r] = v.y * L2E;
    s_xT[(c0 + 2) * RPB + r] = v.z * L2E;
    s_xT[(c0 + 3) * RPB + r] = v.w * L2E;
  }

  // --- zero accumulators ---
#pragma unroll
  for (int k = 0; k < NCLS; ++k) {
    s_acc[k * TPB + t] = 0.0f;
  }

  __syncthreads();

  // --- top of tree: 4 sigmoids give this thread's 4 depth-3 probs ---
  float pl, pr;
  evaln(s_nd, s_xT, 0, row, 1.0f, pl, pr);
  const float pd1 = h ? pr : pl;               // prob of node 1+h
  evaln(s_nd, s_xT, 1 + h, row, pd1, pl, pr);
  const float pA = pl, pB = pr;                // probs of nodes 3+2h, 4+2h
  float pm0, pm1, pm2, pm3;
  evaln(s_nd, s_xT, 3 + 2 * h, row, pA, pm0, pm1);
  evaln(s_nd, s_xT, 4 + 2 * h, row, pB, pm2, pm3);

  // --- 4 depth-3..7 subtrees ---
  const int mb = 7 + 4 * h;
#pragma unroll 1
  for (int s = 0; s < 4; ++s) {
    const float p = (s == 0) ? pm0 : (s == 1) ? pm1 : (s == 2) ? pm2 : pm3;
    dfs<3>(s_nd, s_nd7, s_xT, s_acc, mb + s, t, row, p);
  }

  __syncthreads();                             // cross-thread reads below

  // --- coalesced output write: merge both tree halves ---
  float* og = out + (size_t)blockIdx.x * (RPB * NCLS);
#pragma unroll
  for (int k = 0; k < 5; ++k) {
    const int j = k * TPB + t;                 // 0..1279
    const int r = j / NCLS;                    // magic-mul
    const int c = j - r * NCLS;
    og[j] = s_acc[(c << 8) + r] + s_acc[(c << 8) + RPB + r];
  }
}

extern "C" void kernel_launch(void* const* d_in, const int* in_sizes, int n_in,
                              void* d_out, int out_size, void* d_ws, size_t ws_size,
                              hipStream_t stream) {
  const float* x     = (const float*)d_in[0];
  const float* thr   = (const float*)d_in[1];
  const int*   feats = (const int*)d_in[2];
  const int*   leafc = (const int*)d_in[3];
  float*       out   = (float*)d_out;

  const int B    = in_sizes[0] / NFEAT;        // 131072
  const int grid = B / RPB;                    // 1024

  dt_kernel<<<grid, TPB, 0, stream>>>(x, thr, feats, leafc, out);
}

// Round 2
// 102.155 us; speedup vs baseline: 2.3798x; 2.3798x over previous
//
#include <hip/hip_runtime.h>

// Soft decision tree DEPTH=8, 255 internal nodes (heap order), 256 leaves,
// 10 classes, B=131072, 32 feats. fp32 in/out.
//
// R6 = R4 with the depth-7 leaf accumulation moved from LDS into REGISTERS:
//   - each thread keeps acc[10] (class accumulators) in VGPRs; the class
//     loop is fully unrolled so all indices are compile-time (no scratch),
//   - per leaf-pair: acc[c] += (clsL==c ? pl : 0) + (clsR==c ? pr : 0)
//     -> v_cmp_eq_u32 + v_cndmask + v_add, pure VALU, no DS, no chains,
//   - R5's lesson: ds_add_f32 LDS atomics serialize (~4x slower than R4's
//     RMW chains; 1.65M SQ_LDS_BANK_CONFLICT) -- atomics are out,
//   - R4's lesson: plain LDS RMW is alias-serialized (read->add->write
//     chains) and costs half the DS issue budget -- RMW is out too.
// Accumulation now rides the 4x-parallel per-SIMD VALU pipes instead of the
// CU-shared DS pipe. s_acc arrays deleted; epilogue stages the 10 registers
// through reused s_xT space (16KB >= 10*256*4B).
// LDS/block = 1016 + 2048 + 16384 = 19448 B.
// Unchanged from R4: 2 threads/row (4096 waves), packed node records
// (b64 depths 0..6 / b128 depth 7 incl. leaf classes), transposed
// conflict-free s_xT pre-scaled by log2e, depth-3 probs in regs.

#define NFEAT 32
#define NCLS  10
#define TPB   256
#define RPB   128          // rows per block (2 threads per row)
#define L2E   1.4426950408889634f

__device__ __forceinline__ float fexp2(float z) {
#if __has_builtin(__builtin_amdgcn_exp2f)
  return __builtin_amdgcn_exp2f(z);   // raw v_exp_f32
#else
  return exp2f(z);
#endif
}
__device__ __forceinline__ float frcp(float z) {
#if __has_builtin(__builtin_amdgcn_rcpf)
  return __builtin_amdgcn_rcpf(z);    // raw v_rcp_f32
#else
  return 1.0f / z;
#endif
}

// sigmoid(x-t): e = exp2(t2 - x2); act = 1/(1+e); 1-act = e*act
__device__ __forceinline__ void evaln(const int2* nd, const float* xT,
                                      int n, int row, float p,
                                      float& pl, float& pr) {
  const int2 r = nd[n];                        // ds_read_b64, broadcast (wave-uniform addr)
  const float x2 = xT[(r.y << 7) + row];       // ds_read_b32, lane-linear
  const float e = fexp2(__int_as_float(r.x) - x2);
  const float a = frcp(1.0f + e);
  pr = p * a;
  pl = pr * e;
}

template <int D>
__device__ __forceinline__ void dfs(const int2* nd, const int4* nd7,
                                    const float* xT, float* acc,
                                    int n, int row, float p) {
  if constexpr (D == 7) {
    const int4 r = nd7[n - 127];               // ds_read_b128, broadcast
    const float x2 = xT[(r.y << 7) + row];
    const float e = fexp2(__int_as_float(r.x) - x2);
    const float a = frcp(1.0f + e);
    const float pr = p * a;
    const float pl = pr * e;
    // Branchless register accumulation: v_cmp + v_cndmask + v_add per
    // class-leg. Handles clsL==clsR correctly (both legs add).
#pragma unroll
    for (int c = 0; c < NCLS; ++c) {
      const float aL = (r.z == c) ? pl : 0.0f;
      const float aR = (r.w == c) ? pr : 0.0f;
      acc[c] += aL + aR;
    }
  } else {
    float pl, pr;
    evaln(nd, xT, n, row, p, pl, pr);
    dfs<D + 1>(nd, nd7, xT, acc, 2 * n + 1, row, pl);
    dfs<D + 1>(nd, nd7, xT, acc, 2 * n + 2, row, pr);
  }
}

__global__ __launch_bounds__(TPB, 4)
void dt_kernel(const float* __restrict__ x,
               const float* __restrict__ thr,
               const int*   __restrict__ feats,
               const int*   __restrict__ leafc,
               float*       __restrict__ out) {
  __shared__ int2  s_nd[127];          // depths 0..6: {t*log2e bits, feat}
  __shared__ int4  s_nd7[128];         // depth 7: {t*log2e bits, feat, lcL, lcR}
  __shared__ float s_xT[NFEAT * RPB];  // transposed, pre-scaled by log2e; reused by epilogue

  const int t   = threadIdx.x;
  const int row = t & (RPB - 1);
  const int h   = t >> 7;              // wave-uniform half select

  // --- stage node params (once) ---
  if (t < 127) {
    s_nd[t] = make_int2(__float_as_int(thr[t] * L2E), feats[t]);
  } else if (t < 255) {
    const int n7 = t - 127;
    s_nd7[n7] = make_int4(__float_as_int(thr[t] * L2E), feats[t],
                          leafc[2 * n7], leafc[2 * n7 + 1]);
  }

  // --- stage x: coalesced float4 reads, transposed LDS writes ---
  const float4* xg = (const float4*)x + (size_t)blockIdx.x * (RPB * NFEAT / 4);
#pragma unroll
  for (int k = 0; k < 4; ++k) {
    const int i4 = k * TPB + t;                // 0..1023
    const float4 v = xg[i4];
    const int r  = i4 >> 3;                    // local row
    const int c0 = (i4 & 7) * 4;               // first of 4 feature columns
    s_xT[(c0 + 0) * RPB + r] = v.x * L2E;
    s_xT[(c0 + 1) * RPB + r] = v.y * L2E;
    s_xT[(c0 + 2) * RPB + r] = v.z * L2E;
    s_xT[(c0 + 3) * RPB + r] = v.w * L2E;
  }

  __syncthreads();

  // --- register class accumulators ---
  float acc[NCLS];
#pragma unroll
  for (int c = 0; c < NCLS; ++c) acc[c] = 0.0f;

  // --- top of tree: 4 sigmoids give this thread's 4 depth-3 probs ---
  float pl, pr;
  evaln(s_nd, s_xT, 0, row, 1.0f, pl, pr);
  const float pd1 = h ? pr : pl;               // prob of node 1+h
  evaln(s_nd, s_xT, 1 + h, row, pd1, pl, pr);
  const float pA = pl, pB = pr;                // probs of nodes 3+2h, 4+2h
  float pm0, pm1, pm2, pm3;
  evaln(s_nd, s_xT, 3 + 2 * h, row, pA, pm0, pm1);
  evaln(s_nd, s_xT, 4 + 2 * h, row, pB, pm2, pm3);

  // --- 4 depth-3..7 subtrees, accumulating into registers ---
  const int mb = 7 + 4 * h;
#pragma unroll 1
  for (int s = 0; s < 4; ++s) {
    const float p = (s == 0) ? pm0 : (s == 1) ? pm1 : (s == 2) ? pm2 : pm3;
    dfs<3>(s_nd, s_nd7, s_xT, acc, mb + s, row, p);
  }

  __syncthreads();                             // all s_xT reads done; safe to reuse

  // --- stage register accumulators to LDS (reuse s_xT) ---
  float* s_m = s_xT;                           // [NCLS][TPB] = 10240 B <= 16384 B
#pragma unroll
  for (int c = 0; c < NCLS; ++c) s_m[(c << 8) + t] = acc[c];

  __syncthreads();                             // cross-thread reads below

  // --- coalesced output write: merge both tree halves ---
  float* og = out + (size_t)blockIdx.x * (RPB * NCLS);
#pragma unroll
  for (int k = 0; k < 5; ++k) {
    const int j = k * TPB + t;                 // 0..1279
    const int r = j / NCLS;                    // magic-mul
    const int c = j - r * NCLS;
    og[j] = s_m[(c << 8) + r] + s_m[(c << 8) + RPB + r];
  }
}

extern "C" void kernel_launch(void* const* d_in, const int* in_sizes, int n_in,
                              void* d_out, int out_size, void* d_ws, size_t ws_size,
                              hipStream_t stream) {
  const float* x     = (const float*)d_in[0];
  const float* thr   = (const float*)d_in[1];
  const int*   feats = (const int*)d_in[2];
  const int*   leafc = (const int*)d_in[3];
  float*       out   = (float*)d_out;

  const int B    = in_sizes[0] / NFEAT;        // 131072
  const int grid = B / RPB;                    // 1024

  dt_kernel<<<grid, TPB, 0, stream>>>(x, thr, feats, leafc, out);
}

// Round 3
// 85.250 us; speedup vs baseline: 2.8517x; 1.1983x over previous
//
#include <hip/hip_runtime.h>

// Soft decision tree DEPTH=8, 255 internal nodes (heap order), 256 leaves,
// 10 classes, B=131072, 32 feats. fp32 in/out.
//
// R7: leaf->class reduction recast as MFMA (P[256rows,256leaves] @ onehot),
// node params lane-resident in VGPRs (v_readlane at compile-time lanes),
// 1 thread per row.
//   - R5 lesson: LDS atomics serialize (183us). R6 lesson: 10-way VALU
//     select per leaf is worse than RMW (42us). R4 baseline (26us) was
//     DS-issue-bound: 255 node reads + 255 x reads + 256 RMW per row.
//   - Node (thr,feat) records: lane l holds nodes {2l,2l+1} (depth 0-6) and
//     {127+l, 191+l} (depth 7) in 8 VGPRs; template-unrolled DFS extracts
//     via v_readlane with constant lane -> zero DS for nodes.
//   - Leaf probs written to LDS as f16 in 4 quarters of 64 leaves
//     ([256][64] f16 = 32KB, XOR swizzle ((r^(r>>3))&7)<<4 => conflict-free
//     b128 writes AND fragment reads), consumed by mfma_f32_16x16x32_f16
//     with B = onehot fragments built once in registers from leafc.
//     Within-lane k-order of A/B fragments cancels; only A-row=lane&15,
//     B-col=lane&15 and the verified C/D layout (col=lane&15,
//     row=(lane>>4)*4+reg) are load-bearing.
//   - No accumulator arrays passed by pointer (R6 SROA suspicion): leaf
//     packs are 4 named words -> one b128 store per depth-5 subtree.
// LDS = s_xT 32x257 f32 (32.9KB, padded pitch: conflict-free transpose)
//     + s_P 32KB + s_lc 1KB = 66.7KB -> 2 blocks/CU.

#define NFEAT 32
#define NCLS  10
#define TPB   256        // 1 thread per row
#define RPB   256        // rows per block
#define XPITCH 257       // padded f32 pitch for s_xT
#define L2E   1.4426950408889634f

typedef _Float16 f16x8 __attribute__((ext_vector_type(8)));
typedef float    f32x4 __attribute__((ext_vector_type(4)));

__device__ __forceinline__ float fexp2(float z) {
#if __has_builtin(__builtin_amdgcn_exp2f)
  return __builtin_amdgcn_exp2f(z);
#else
  return exp2f(z);
#endif
}
__device__ __forceinline__ float frcp(float z) {
#if __has_builtin(__builtin_amdgcn_rcpf)
  return __builtin_amdgcn_rcpf(z);
#else
  return 1.0f / z;
#endif
}
__device__ __forceinline__ float rlf(float v, int lane) {
  return __int_as_float(__builtin_amdgcn_readlane(__float_as_int(v), lane));
}
__device__ __forceinline__ int rli(int v, int lane) {
  return __builtin_amdgcn_readlane(v, lane);
}

// Lane-resident node records (pre-scaled thresholds, thr*log2e).
struct NodeRegs {
  float t0, t1;   // depth 0-6: node n -> lane n>>1, member n&1
  int   f0, f1;
  float t7a, t7b; // depth 7: node m=N-127 -> lane m&63, member m>>6
  int   f7a, f7b;
};

// sigmoid(x-t) with exp2: e = exp2(t2 - x2); a = 1/(1+e); pr=p*a; pl=pr*e.
template <int N>
__device__ __forceinline__ void evalN(const NodeRegs& R, const float* xT,
                                      int row, float p, float& pl, float& pr) {
  float sthr; int sfeat;
  if constexpr (N < 127) {
    sthr  = rlf((N & 1) ? R.t1 : R.t0, N >> 1);
    sfeat = rli((N & 1) ? R.f1 : R.f0, N >> 1);
  } else {
    constexpr int m = N - 127;
    sthr  = rlf((m >> 6) ? R.t7b : R.t7a, m & 63);
    sfeat = rli((m >> 6) ? R.f7b : R.f7a, m & 63);
  }
  const float x2 = xT[sfeat * XPITCH + row];
  const float e  = fexp2(sthr - x2);
  const float a  = frcp(1.0f + e);
  pr = p * a;
  pl = pr * e;
}

// Depth-7 node: pack the two leaf probs as half2 (low = left leaf).
template <int N>
__device__ __forceinline__ unsigned leafpair(const NodeRegs& R, const float* xT,
                                             int row, float p) {
  float pl, pr;
  evalN<N>(R, xT, row, p, pl, pr);
  const _Float16 hl = (_Float16)pl, hr = (_Float16)pr;
  return ((unsigned)__builtin_bit_cast(unsigned short, hr) << 16) |
          (unsigned)__builtin_bit_cast(unsigned short, hl);
}

// Depth-5 subtree: 8 leaves -> 4 named words -> one swizzled b128 store.
template <int N>
__device__ __forceinline__ void d5block(const NodeRegs& R, const float* xT,
                                        int row, float p, char* rowp,
                                        int swz, int pb4) {
  float pl, pr;
  evalN<N>(R, xT, row, p, pl, pr);
  float qll, qlr, qrl, qrr;
  evalN<2 * N + 1>(R, xT, row, pl, qll, qlr);
  evalN<2 * N + 2>(R, xT, row, pr, qrl, qrr);
  uint4 u;
  u.x = leafpair<4 * N + 3>(R, xT, row, qll);
  u.y = leafpair<4 * N + 4>(R, xT, row, qlr);
  u.z = leafpair<4 * N + 5>(R, xT, row, qrl);
  u.w = leafpair<4 * N + 6>(R, xT, row, qrr);
  *(uint4*)(rowp + (pb4 ^ swz)) = u;
}

// Depths 3..4 of the DFS; pb4 = byte offset of this subtree's leaf packs.
template <int D, int N>
__device__ __forceinline__ void dfs(const NodeRegs& R, const float* xT, int row,
                                    float p, char* rowp, int swz, int pb4) {
  if constexpr (D == 5) {
    d5block<N>(R, xT, row, p, rowp, swz, pb4);
  } else {
    float pl, pr;
    evalN<N>(R, xT, row, p, pl, pr);
    dfs<D + 1, 2 * N + 1>(R, xT, row, pl, rowp, swz, pb4);
    dfs<D + 1, 2 * N + 2>(R, xT, row, pr, rowp, swz, pb4 + (1 << (8 - D)));
  }
}

__global__ __launch_bounds__(TPB, 2)
void dt_kernel(const float* __restrict__ x,
               const float* __restrict__ thr,
               const int*   __restrict__ feats,
               const int*   __restrict__ leafc,
               float*       __restrict__ out) {
  __shared__ float s_xT[NFEAT * XPITCH];            // transposed x, *log2e
  __shared__ __align__(16) char s_P[RPB * 128];     // quarter of P, f16, swizzled
  __shared__ int s_lc[256];                         // leaf classes

  const int t    = threadIdx.x;
  const int lane = t & 63;

  // --- lane-resident node records (global loads, L2-hit after 1st block) ---
  NodeRegs R;
  {
    const float2 tv = *(const float2*)(thr + 2 * lane);   // 8B aligned
    const int2   fv = *(const int2*)(feats + 2 * lane);
    R.t0 = tv.x * L2E; R.t1 = tv.y * L2E;
    R.f0 = fv.x;       R.f1 = fv.y;
    R.t7a = thr[127 + lane] * L2E;
    R.t7b = thr[191 + lane] * L2E;
    R.f7a = feats[127 + lane];
    R.f7b = feats[191 + lane];
  }

  // --- stage x (coalesced float4, transposed, padded pitch) + leafc ---
  const float4* xg = (const float4*)x + (size_t)blockIdx.x * (RPB * NFEAT / 4);
#pragma unroll
  for (int k = 0; k < 8; ++k) {
    const int i4 = k * TPB + t;                 // 0..2047
    const float4 v = xg[i4];
    const int r  = i4 >> 3;
    const int c0 = (i4 & 7) * 4;
    s_xT[(c0 + 0) * XPITCH + r] = v.x * L2E;
    s_xT[(c0 + 1) * XPITCH + r] = v.y * L2E;
    s_xT[(c0 + 2) * XPITCH + r] = v.z * L2E;
    s_xT[(c0 + 3) * XPITCH + r] = v.w * L2E;
  }
  s_lc[t] = leafc[t];

  __syncthreads();

  // --- B fragments: onehot(leafc) in registers, chunk c = leaves [32c,32c+32) ---
  // lane: col = lane&15, k-local = (lane>>4)*8 + j  (same k-labeling as A).
  f16x8 Bf[8];
  {
    const int col = lane & 15;
    const int kb  = (lane >> 4) * 8;
#pragma unroll
    for (int c = 0; c < 8; ++c) {
      const int4 cA = *(const int4*)&s_lc[c * 32 + kb];
      const int4 cB = *(const int4*)&s_lc[c * 32 + kb + 4];
      uint4 u;
      u.x = ((cA.x == col) ? 0x3C00u : 0u) | (((cA.y == col) ? 0x3C00u : 0u) << 16);
      u.y = ((cA.z == col) ? 0x3C00u : 0u) | (((cA.w == col) ? 0x3C00u : 0u) << 16);
      u.z = ((cB.x == col) ? 0x3C00u : 0u) | (((cB.y == col) ? 0x3C00u : 0u) << 16);
      u.w = ((cB.z == col) ? 0x3C00u : 0u) | (((cB.w == col) ? 0x3C00u : 0u) << 16);
      Bf[c] = __builtin_bit_cast(f16x8, u);
    }
  }

  // --- top of tree: 8 depth-3 probs in registers ---
  float p1l, p1r, p2a, p2b, p2c, p2d;
  evalN<0>(R, s_xT, t, 1.0f, p1l, p1r);
  evalN<1>(R, s_xT, t, p1l, p2a, p2b);
  evalN<2>(R, s_xT, t, p1r, p2c, p2d);
  float p30, p31, p32, p33, p34, p35, p36, p37;
  evalN<3>(R, s_xT, t, p2a, p30, p31);
  evalN<4>(R, s_xT, t, p2b, p32, p33);
  evalN<5>(R, s_xT, t, p2c, p34, p35);
  evalN<6>(R, s_xT, t, p2d, p36, p37);

  // --- 4 quarters: DFS -> swizzled f16 P tile -> 2 MFMAs per row-tile ---
  const int swz   = ((t ^ (t >> 3)) & 7) << 4;
  char* rowp      = s_P + t * 128;
  const int wv    = t >> 6;
  const int col16 = lane & 15;
  const int kgrpB = (lane >> 4) * 16;             // byte offset of 8-f16 group

  f32x4 acc[4];
#pragma unroll
  for (int i = 0; i < 4; ++i) acc[i] = (f32x4){0.f, 0.f, 0.f, 0.f};

#define QUARTER(Q, PA, PB_)                                                  \
  {                                                                          \
    __syncthreads(); /* prev MFMA done reading s_P */                        \
    dfs<3, 7 + 2 * Q>(R, s_xT, t, PA, rowp, swz, 0);                         \
    dfs<3, 8 + 2 * Q>(R, s_xT, t, PB_, rowp, swz, 64);                       \
    __syncthreads(); /* P quarter ready */                                   \
    _Pragma("unroll")                                                        \
    for (int i = 0; i < 4; ++i) {                                            \
      const int arow = (wv * 4 + i) * 16 + col16;                            \
      const int aswz = ((arow ^ (arow >> 3)) & 7) << 4;                      \
      const char* ap = s_P + arow * 128;                                     \
      const f16x8 a0 = *(const f16x8*)(ap + ((kgrpB)      ^ aswz));          \
      const f16x8 a1 = *(const f16x8*)(ap + ((kgrpB + 64) ^ aswz));          \
      acc[i] = __builtin_amdgcn_mfma_f32_16x16x32_f16(a0, Bf[2 * Q],         \
                                                      acc[i], 0, 0, 0);      \
      acc[i] = __builtin_amdgcn_mfma_f32_16x16x32_f16(a1, Bf[2 * Q + 1],     \
                                                      acc[i], 0, 0, 0);      \
    }                                                                        \
  }

  QUARTER(0, p30, p31)
  QUARTER(1, p32, p33)
  QUARTER(2, p34, p35)
  QUARTER(3, p36, p37)
#undef QUARTER

  // --- epilogue: D layout col=lane&15, row=(lane>>4)*4+reg (m89-verified) ---
  const int col = lane & 15;
  if (col < NCLS) {
    const size_t rbase = (size_t)blockIdx.x * RPB + wv * 64 + (lane >> 4) * 4;
#pragma unroll
    for (int i = 0; i < 4; ++i) {
#pragma unroll
      for (int j = 0; j < 4; ++j) {
        out[(rbase + i * 16 + j) * NCLS + col] = acc[i][j];
      }
    }
  }
}

extern "C" void kernel_launch(void* const* d_in, const int* in_sizes, int n_in,
                              void* d_out, int out_size, void* d_ws, size_t ws_size,
                              hipStream_t stream) {
  const float* x     = (const float*)d_in[0];
  const float* thr   = (const float*)d_in[1];
  const int*   feats = (const int*)d_in[2];
  const int*   leafc = (const int*)d_in[3];
  float*       out   = (float*)d_out;

  const int B    = in_sizes[0] / NFEAT;        // 131072
  const int grid = B / RPB;                    // 512

  dt_kernel<<<grid, TPB, 0, stream>>>(x, thr, feats, leafc, out);
}